// Round 11
// baseline (61.325 us; speedup 1.0000x reference)
//
#include <hip/hip_runtime.h>
#include <stdint.h>

#define SEQ 2048
#define BATCH 4
#define EMB 512
#define MTOT (BATCH * SEQ)   // 8192 rows
#define WIN 16
#define WINDOW 33            // 2*WIN+1

typedef uint32_t u32;
typedef unsigned short u16;
typedef __attribute__((ext_vector_type(8))) __bf16 bf16x8;
typedef __attribute__((ext_vector_type(4))) float f32x4;
typedef __attribute__((ext_vector_type(4))) u16 u16x4;
typedef __attribute__((ext_vector_type(8))) u16 u16x8;

__device__ __forceinline__ u16 f2bf(float f) {  // RNE f32->bf16
  u32 u = __builtin_bit_cast(u32, f);
  u = (u + 0x7fffu + ((u >> 16) & 1u)) >> 16;
  return (u16)u;
}
__device__ __forceinline__ float bf2f(u16 v) {
  return __builtin_bit_cast(float, (u32)v << 16);
}
__device__ __forceinline__ void gload16(void* lds, const void* g) {
  __builtin_amdgcn_global_load_lds((const __attribute__((address_space(1))) u32*)g,
                                   (__attribute__((address_space(3))) u32*)lds, 16, 0, 0);
}
// Explicit drain of LDS-DMA (vm) + ds ops (lgkm) before a publishing barrier.
// R5/R6 lesson: never rely on the compiler emitting this for DMA-staged LDS.
__device__ __forceinline__ void drain_stage() {
  asm volatile("s_waitcnt vmcnt(0) lgkmcnt(0)" ::: "memory");
}

// ============ launch 1: prep4 — weight casts only (x-cast moved into gemm_qk2) ============
// [0,256): Wq->Wqb | [256,512): Wk->Wkb | [512,768): Wo->Wob | [768,1024): Wv->WvT
// [1024,1032): bc[i] = Wo[i,:].bv + bo[i] | [1032]: econst = bq.bk
__global__ void __launch_bounds__(256) prep4(
    const float* __restrict__ Wq, const float* __restrict__ Wk,
    const float* __restrict__ Wv, const float* __restrict__ Wo,
    const float* __restrict__ bq, const float* __restrict__ bk,
    const float* __restrict__ bv, const float* __restrict__ bo,
    u16* __restrict__ Wqb, u16* __restrict__ Wkb, u16* __restrict__ Wob,
    u16* __restrict__ WvT, float* __restrict__ bc, float* __restrict__ econst) {
  __shared__ float sm[32][33];
  int b = blockIdx.x, t = threadIdx.x;
  if (b < 768) {                          // ---- Wq / Wk / Wo casts
    const float* S = (b < 256) ? Wq : (b < 512) ? Wk : Wo;
    u16* D = (b < 256) ? Wqb : (b < 512) ? Wkb : Wob;
    int cb = b & 255;
    int i = (cb * 256 + t) * 4;
    float4 v = *reinterpret_cast<const float4*>(S + i);
    u16x4 o; o.x = f2bf(v.x); o.y = f2bf(v.y); o.z = f2bf(v.z); o.w = f2bf(v.w);
    *reinterpret_cast<u16x4*>(D + i) = o;
  } else if (b < 1024) {                  // ---- WvT[j][k] = Wv[k][j] (32x32 tile)
    int tb = b - 768;
    int ti = tb >> 4, tj = tb & 15;
    int lr = t >> 5, lc = t & 31;
#pragma unroll
    for (int rr = 0; rr < 32; rr += 8)
      sm[rr + lr][lc] = Wv[(size_t)(ti * 32 + rr + lr) * EMB + tj * 32 + lc];
    __syncthreads();
    int jr = t >> 3, dc = (t & 7) * 4;
    u16x4 o;
#pragma unroll
    for (int c = 0; c < 4; ++c) o[c] = f2bf(sm[dc + c][jr]);
    *reinterpret_cast<u16x4*>(WvT + (size_t)(tj * 32 + jr) * EMB + ti * 32 + dc) = o;
  } else if (b < 1032) {                  // ---- bc
    float* sh = &sm[0][0];
    int cb = b - 1024;
    int ii = t >> 2, di = t & 3;
    int i = cb * 64 + ii;
    float s = 0.f;
    for (int d = di * 128; d < di * 128 + 128; ++d)
      s += Wo[(size_t)i * EMB + d] * bv[d];
    sh[t] = s;
    __syncthreads();
    if (di == 0) bc[i] = sh[t] + sh[t + 1] + sh[t + 2] + sh[t + 3] + bo[i];
  } else {                                // ---- econst = bq.bk
    float* sh = &sm[0][0];
    float s = bq[t] * bk[t] + bq[t + 256] * bk[t + 256];
    sh[t] = s;
    __syncthreads();
    for (int st = 128; st > 0; st >>= 1) {
      if (t < st) sh[t] += sh[t + st];
      __syncthreads();
    }
    if (t == 0) *econst = sh[0];
  }
}

// ============ launch 2: gemm_qk2 — e via direct (Q+bq).(K+bk), 64x64 tiles, 1024 blocks ====
// A (x-tile) reg-cast-staged from fp32; by==0 blocks also emit xb (bf16 x) for launch 3.
// Q/K weight tiles via global_load_lds DMA. slot = by*2+wc (16 slots).
__global__ void __launch_bounds__(256) gemm_qk2(
    const float* __restrict__ x, const u16* __restrict__ Wqb, const u16* __restrict__ Wkb,
    const float* __restrict__ bq, const float* __restrict__ bk,
    float* __restrict__ e_part, u16* __restrict__ xb) {
  __shared__ u16 XL[64 * 32];     // 4 KB
  __shared__ u16 QL[64 * 32];     // 4 KB
  __shared__ u16 KL[64 * 32];     // 4 KB -> 12 KB total, ~5 blocks/CU
  int b = blockIdx.x;                    // 1024 blocks
  int wg = ((b & 7) << 7) + (b >> 3);    // XCD-chunked swizzle (1024 = 8*128)
  int by = wg & 7, bx = wg >> 3;
  int t = threadIdx.x;
  int wave = t >> 6, lane = t & 63;
  int wr = wave >> 1, wc = wave & 1;
  int fr = lane & 15, fq = lane >> 4;
  int m0 = bx * 64, n0 = by * 64;
  bool emitX = (by == 0);
  int srow = t >> 2, sc8 = (t & 3) * 8;  // staging coords: row 0..63, col8 0,8,16,24
  f32x4 accQ[2][2] = {};
  f32x4 accK[2][2] = {};
  for (int kt = 0; kt < 16; ++kt) {
    __syncthreads();                     // prior-iter frag reads consumed
    int kb = kt * 32;
    // Q/K tiles: DMA (chunk t -> dest t*16B, per-lane src)
    gload16(QL + (size_t)t * 8, Wqb + (size_t)(n0 + srow) * EMB + kb + sc8);
    gload16(KL + (size_t)t * 8, Wkb + (size_t)(n0 + srow) * EMB + kb + sc8);
    // A tile: fp32 x -> cast -> LDS (+ xb side-effect for by==0)
    {
      const float* xs = x + (size_t)(m0 + srow) * EMB + kb + sc8;
      float4 v0 = *reinterpret_cast<const float4*>(xs);
      float4 v1 = *reinterpret_cast<const float4*>(xs + 4);
      u16x8 a8;
      a8[0] = f2bf(v0.x); a8[1] = f2bf(v0.y); a8[2] = f2bf(v0.z); a8[3] = f2bf(v0.w);
      a8[4] = f2bf(v1.x); a8[5] = f2bf(v1.y); a8[6] = f2bf(v1.z); a8[7] = f2bf(v1.w);
      *reinterpret_cast<u16x8*>(&XL[srow * 32 + sc8]) = a8;
      if (emitX)
        *reinterpret_cast<u16x8*>(xb + (size_t)(m0 + srow) * EMB + kb + sc8) = a8;
    }
    drain_stage();                       // DMA + ds_writes (+stores) landed before publish
    __syncthreads();
    bf16x8 af[2];
#pragma unroll
    for (int m = 0; m < 2; ++m)
      af[m] = *reinterpret_cast<const bf16x8*>(&XL[(wr * 32 + m * 16 + fr) * 32 + fq * 8]);
#pragma unroll
    for (int n = 0; n < 2; ++n) {
      bf16x8 q8 = *reinterpret_cast<const bf16x8*>(&QL[(wc * 32 + n * 16 + fr) * 32 + fq * 8]);
#pragma unroll
      for (int m = 0; m < 2; ++m)
        accQ[m][n] = __builtin_amdgcn_mfma_f32_16x16x32_bf16(af[m], q8, accQ[m][n], 0, 0, 0);
      bf16x8 k8 = *reinterpret_cast<const bf16x8*>(&KL[(wc * 32 + n * 16 + fr) * 32 + fq * 8]);
#pragma unroll
      for (int m = 0; m < 2; ++m)
        accK[m][n] = __builtin_amdgcn_mfma_f32_16x16x32_bf16(af[m], k8, accK[m][n], 0, 0, 0);
    }
  }
  float bqv[2], bkv[2];
#pragma unroll
  for (int n = 0; n < 2; ++n) {
    int col = n0 + wc * 32 + n * 16 + fr;
    bqv[n] = bq[col];
    bkv[n] = bk[col];
  }
  int slot = by * 2 + wc;
#pragma unroll
  for (int m = 0; m < 2; ++m) {
#pragma unroll
    for (int r = 0; r < 4; ++r) {
      int row = m0 + wr * 32 + m * 16 + fq * 4 + r;
      float p = 0.f;
#pragma unroll
      for (int n = 0; n < 2; ++n)
        p += (accQ[m][n][r] + bqv[n]) * (accK[m][n][r] + bkv[n]);
      p += __shfl_xor(p, 1);
      p += __shfl_xor(p, 2);
      p += __shfl_xor(p, 4);
      p += __shfl_xor(p, 8);
      if (fr == 0) e_part[(size_t)slot * MTOT + row] = p;
    }
  }
}

// ============ launch 3: window softmax + weighted x-sum -> y  ||  Wc = Wo@Wv (MFMA) ========
// blocks [0,512): window (reads xb, e_part; writes y)
// blocks [512,576): Wc 64x64 tiles (reads Wob, WvT; writes Wcb — consumed only by launch 4)
__global__ void __launch_bounds__(256) window3(
    const u16* __restrict__ xb, const float* __restrict__ e_part,
    const float* __restrict__ econst_p, u16* __restrict__ y,
    const u16* __restrict__ Wob, const u16* __restrict__ WvT, u16* __restrict__ Wcb) {
  __shared__ __align__(16) char smem[51456];
  int b = blockIdx.x;
  int t = threadIdx.x;
  if (b >= 512) {                        // ---- Wc tile: 64x64, BK=32, DMA-staged
    u16* AL = (u16*)smem;                // 64x32 = 4 KB
    u16* BL = (u16*)(smem + 4096);       // 64x32 = 4 KB
    int wcb = b - 512;
    int i0 = (wcb >> 3) * 64, j0 = (wcb & 7) * 64;
    int wave = t >> 6, lane = t & 63;
    int wr = wave >> 1, wc = wave & 1;
    int fr = lane & 15, fq = lane >> 4;
    f32x4 acc[2][2] = {};
    for (int kt = 0; kt < 16; ++kt) {
      __syncthreads();
      int kb = kt * 32;
      int row = t >> 2, col8 = (t & 3) * 8;
      gload16(AL + (size_t)t * 8, Wob + (size_t)(i0 + row) * EMB + kb + col8);
      gload16(BL + (size_t)t * 8, WvT + (size_t)(j0 + row) * EMB + kb + col8);
      drain_stage();
      __syncthreads();
      bf16x8 af[2], bfv[2];
#pragma unroll
      for (int m = 0; m < 2; ++m)
        af[m] = *reinterpret_cast<const bf16x8*>(&AL[(wr * 32 + m * 16 + fr) * 32 + fq * 8]);
#pragma unroll
      for (int n = 0; n < 2; ++n)
        bfv[n] = *reinterpret_cast<const bf16x8*>(&BL[(wc * 32 + n * 16 + fr) * 32 + fq * 8]);
#pragma unroll
      for (int m = 0; m < 2; ++m)
#pragma unroll
        for (int n = 0; n < 2; ++n)
          acc[m][n] = __builtin_amdgcn_mfma_f32_16x16x32_bf16(af[m], bfv[n], acc[m][n], 0, 0, 0);
    }
#pragma unroll
    for (int m = 0; m < 2; ++m)
#pragma unroll
      for (int n = 0; n < 2; ++n)
#pragma unroll
        for (int r = 0; r < 4; ++r)
          Wcb[(size_t)(i0 + wr * 32 + m * 16 + fq * 4 + r) * EMB + j0 + wc * 32 + n * 16 + fr] =
              f2bf(acc[m][n][r]);
    return;
  }
  // ---- window path ----
  u16* Xt = (u16*)smem;                                    // 48 x 512 bf16 = 49152 B
  float* eloc = (float*)(smem + 49152);                    // 48
  float (*w)[WINDOW] = (float (*)[WINDOW])(smem + 49344);  // 16 x 33
  int swz = ((b & 7) << 6) + (b >> 3);   // XCD-chunked
  int bb = swz >> 7;
  int s0 = (swz & 127) * 16;
  // stage 48 x rows (zeros for pads): reg-staged (R6 lesson: no divergent-source DMA)
  u16x8 stg[12];
#pragma unroll
  for (int i = 0; i < 12; ++i) {
    int chunk = t + i * 256;
    int row = chunk >> 6;
    int c8 = (chunk & 63) * 8;
    int n = s0 + row - WIN;
    if (n >= 0 && n < SEQ)
      stg[i] = *reinterpret_cast<const u16x8*>(xb + (size_t)(bb * SEQ + n) * EMB + c8);
    else
      stg[i] = (u16x8){0, 0, 0, 0, 0, 0, 0, 0};
  }
#pragma unroll
  for (int i = 0; i < 12; ++i) {
    int chunk = t + i * 256;
    int row = chunk >> 6;
    int c8 = (chunk & 63) * 8;
    *reinterpret_cast<u16x8*>(&Xt[(size_t)row * EMB + c8]) = stg[i];
  }
  const float scale = 0.044194173824159216f;  // 1/sqrt(512)
  float ec = *econst_p;
  if (t < 48) {
    int n = s0 + t - WIN;
    float raw = 0.f;
    if (n >= 0 && n < SEQ) {
      size_t idx = (size_t)bb * SEQ + n;
#pragma unroll
      for (int p = 0; p < 16; ++p) raw += e_part[(size_t)p * MTOT + idx];
    }
    eloc[t] = scale * (raw + ec);        // pad: raw==0 -> scale*bq.bk, exact
  }
  __syncthreads();
  if (t < 16) {
    float ev[WINDOW];
    float mx = -1e30f;
#pragma unroll
    for (int j = 0; j < WINDOW; ++j) { ev[j] = eloc[t + j]; mx = fmaxf(mx, ev[j]); }
    float sum = 0.f;
#pragma unroll
    for (int j = 0; j < WINDOW; ++j) { float ex = __expf(ev[j] - mx); ev[j] = ex; sum += ex; }
    float inv = 1.f / sum;
#pragma unroll
    for (int j = 0; j < WINDOW; ++j) w[t][j] = ev[j] * inv;
  }
  __syncthreads();
  int cg = t & 63;
  int slg = t >> 6;
  int d0 = cg * 8;
  float oacc[4][8] = {};
  for (int ri = 0; ri < 36; ++ri) {
    int r = slg * 4 + ri;
    u16x8 v = *reinterpret_cast<const u16x8*>(&Xt[(size_t)r * EMB + d0]);
    float vf[8];
#pragma unroll
    for (int c = 0; c < 8; ++c) vf[c] = bf2f(v[c]);
#pragma unroll
    for (int q = 0; q < 4; ++q) {
      int j = ri - q;
      if (j >= 0 && j < WINDOW) {
        float wt = w[slg * 4 + q][j];
#pragma unroll
        for (int c = 0; c < 8; ++c) oacc[q][c] += wt * vf[c];
      }
    }
  }
#pragma unroll
  for (int q = 0; q < 4; ++q) {
    u16x8 o;
#pragma unroll
    for (int c = 0; c < 8; ++c) o[c] = f2bf(oacc[q][c]);
    *reinterpret_cast<u16x8*>(&y[(size_t)(bb * SEQ + s0 + slg * 4 + q) * EMB + d0]) = o;
  }
}

// ============ launch 4: out = y @ Wc^T + bc (fp32); both operands via DMA ============
__global__ void __launch_bounds__(256) gemm_o(
    const u16* __restrict__ y, const u16* __restrict__ Wcb,
    const float* __restrict__ bc, float* __restrict__ out) {
  __shared__ u16 At2[64 * 32];    // 4 KB
  __shared__ u16 Bt2[128 * 32];   // 8 KB
  int b = blockIdx.x;                    // 512 blocks
  int wg = ((b & 7) << 6) + (b >> 3);    // XCD-chunked swizzle
  int bx = wg >> 2, by = wg & 3;
  int t = threadIdx.x;
  int wave = t >> 6, lane = t & 63;
  int wr = wave >> 1, wc = wave & 1;
  int fr = lane & 15, fq = lane >> 4;
  int m0 = bx * 64, n0 = by * 128;
  f32x4 acc[2][4] = {};
  for (int kt = 0; kt < EMB / 32; ++kt) {
    __syncthreads();
    int kb = kt * 32;
    {
      int row = t >> 2, col = (t & 3) * 8;
      gload16(At2 + (size_t)t * 8, y + (size_t)(m0 + row) * EMB + kb + col);
    }
#pragma unroll
    for (int it = 0; it < 2; ++it) {
      int chunk = t + it * 256;
      int row = chunk >> 2, col = (chunk & 3) * 8;
      gload16(Bt2 + (size_t)(wave * 64 + it * 256) * 8, Wcb + (size_t)(n0 + row) * EMB + kb + col);
    }
    drain_stage();
    __syncthreads();
    bf16x8 af[2], bfv[4];
#pragma unroll
    for (int m = 0; m < 2; ++m)
      af[m] = *reinterpret_cast<const bf16x8*>(&At2[(wr * 32 + m * 16 + fr) * 32 + fq * 8]);
#pragma unroll
    for (int n = 0; n < 4; ++n)
      bfv[n] = *reinterpret_cast<const bf16x8*>(&Bt2[(wc * 64 + n * 16 + fr) * 32 + fq * 8]);
#pragma unroll
    for (int m = 0; m < 2; ++m)
#pragma unroll
      for (int n = 0; n < 4; ++n)
        acc[m][n] = __builtin_amdgcn_mfma_f32_16x16x32_bf16(af[m], bfv[n], acc[m][n], 0, 0, 0);
  }
  float bcv[4];
#pragma unroll
  for (int n = 0; n < 4; ++n) bcv[n] = bc[n0 + wc * 64 + n * 16 + fr];
#pragma unroll
  for (int m = 0; m < 2; ++m)
#pragma unroll
    for (int n = 0; n < 4; ++n) {
      int col = n0 + wc * 64 + n * 16 + fr;
#pragma unroll
      for (int r = 0; r < 4; ++r) {
        int row = m0 + wr * 32 + m * 16 + fq * 4 + r;
        out[(size_t)row * EMB + col] = acc[m][n][r] + bcv[n];
      }
    }
}

extern "C" void kernel_launch(void* const* d_in, const int* in_sizes, int n_in,
                              void* d_out, int out_size, void* d_ws, size_t ws_size,
                              hipStream_t stream) {
  const float* x  = (const float*)d_in[0];
  const float* Wq = (const float*)d_in[1];
  const float* bq = (const float*)d_in[2];
  const float* Wk = (const float*)d_in[3];
  const float* bk = (const float*)d_in[4];
  const float* Wv = (const float*)d_in[5];
  const float* bv = (const float*)d_in[6];
  const float* Wo = (const float*)d_in[7];
  const float* bo = (const float*)d_in[8];
  float* out = (float*)d_out;

  char* ws = (char*)d_ws;
  u16* xb       = (u16*)(ws);                                    // 8 MB
  u16* y        = (u16*)(ws + (8u << 20));                       // 8 MB
  u16* Wqb      = (u16*)(ws + (16u << 20));                      // 512 KB
  u16* Wkb      = (u16*)(ws + (16u << 20) + (512u << 10));       // 512 KB
  u16* Wob      = (u16*)(ws + (16u << 20) + (1024u << 10));      // 512 KB
  u16* WvT      = (u16*)(ws + (16u << 20) + (1536u << 10));      // 512 KB
  u16* Wcb      = (u16*)(ws + (16u << 20) + (2048u << 10));      // 512 KB
  float* e_part = (float*)(ws + (16u << 20) + (2560u << 10));    // 512 KB (16 slots)
  float* bc     = (float*)(ws + (16u << 20) + (3072u << 10));    // 2 KB
  float* econst = (float*)(ws + (16u << 20) + (3074u << 10));    // 4 B

  // 1) weight casts + bc + econst (x-cast eliminated — qk2 produces xb)
  prep4<<<1033, 256, 0, stream>>>(Wq, Wk, Wv, Wo, bq, bk, bv, bo,
                                  Wqb, Wkb, Wob, WvT, bc, econst);
  // 2) e = (Q+bq).(K+bk); A self-staged from fp32 x; by==0 emits xb
  gemm_qk2<<<1024, 256, 0, stream>>>(x, Wqb, Wkb, bq, bk, e_part, xb);
  // 3) window softmax + weighted x-sum -> y  ||  Wc = Wo@Wv (MFMA)
  window3<<<576, 256, 0, stream>>>(xb, e_part, econst, y, Wob, WvT, Wcb);
  // 4) out = y @ Wc^T + bc
  gemm_o<<<512, 256, 0, stream>>>(y, Wcb, bc, out);
}